// Round 4
// baseline (119.123 us; speedup 1.0000x reference)
//
#include <hip/hip_runtime.h>
#include <hip/hip_bf16.h>
#include <math.h>

#define N_SPANS 4096
#define EMB 384
#define HEADS 4
#define HE (HEADS * EMB)   // 1536
#define BAND 11            // exp(-12/5)=0.0907 < 0.1 => |i-j|>=12 never passes threshold
#define BW (2 * BAND + 1)  // 23

typedef short bf16x8 __attribute__((ext_vector_type(8)));
typedef float f32x4 __attribute__((ext_vector_type(4)));

__device__ __forceinline__ unsigned short f2bf(float f) {
    union { float f; unsigned u; } x; x.f = f;
    unsigned r = x.u + 0x7fffu + ((x.u >> 16) & 1u);  // RNE
    return (unsigned short)(r >> 16);
}
__device__ __forceinline__ float bf2f(unsigned short u) {
    union { unsigned u; float f; } x; x.u = ((unsigned)u) << 16; return x.f;
}

__device__ __forceinline__ float wave_sum(float v) {
    #pragma unroll
    for (int off = 32; off; off >>= 1) v += __shfl_xor(v, off, 64);
    return v;
}
__device__ __forceinline__ float wave_max(float v) {
    #pragma unroll
    for (int off = 32; off; off >>= 1) v = fmaxf(v, __shfl_xor(v, off, 64));
    return v;
}

// async global->LDS, 16B per lane, dest = wave-uniform base + lane*16
__device__ __forceinline__ void gl2lds16(const void* g, void* l) {
    __builtin_amdgcn_global_load_lds(
        (const __attribute__((address_space(1))) void*)(uintptr_t)g,
        (__attribute__((address_space(3))) void*)(unsigned)(uintptr_t)l,
        16, 0, 0);
}

// ------------------------------------------------------------------ prep
// blocks [0,1024): wave per node n: inv-norm + Ebf cast + forward band dots d=1..11
// blocks [1024,1600): W [384,1536] -> Wt bf16 [1536,384]
// blocks [1600,1632): zero asrc/adst (32768 floats)
__global__ __launch_bounds__(256) void prep(const float* __restrict__ E,
                                            const float* __restrict__ W,
                                            unsigned short* __restrict__ Ebf,
                                            unsigned short* __restrict__ Wt,
                                            float* __restrict__ invn,
                                            float* __restrict__ Dots,
                                            float* __restrict__ attacc) {
    __shared__ float tile[32][33];
    const int b = blockIdx.x;
    const int tid = threadIdx.x;
    if (b < 1024) {
        const int lane = tid & 63, w = tid >> 6;
        const int n = b * 4 + w;
        const float4* er4 = (const float4*)(E + (size_t)n * EMB);
        const int dmax = (n >= N_SPANS - BAND) ? (N_SPANS - 1 - n) : BAND;  // wave-uniform
        const float4* nb4[BAND];
        #pragma unroll
        for (int d = 1; d <= BAND; ++d) {
            int j = n + d; if (j > N_SPANS - 1) j = N_SPANS - 1;  // clamped, in-bounds
            nb4[d - 1] = (const float4*)(E + (size_t)j * EMB);
        }
        float acc[12];
        #pragma unroll
        for (int d = 0; d < 12; ++d) acc[d] = 0.f;
        #pragma unroll
        for (int mq = 0; mq < 2; ++mq) {
            const int idx = mq * 64 + lane;   // float4 index over 96
            if (idx < 96) {
                float4 v = er4[idx];
                acc[0] += v.x * v.x + v.y * v.y + v.z * v.z + v.w * v.w;
                ushort4 pb;
                pb.x = f2bf(v.x); pb.y = f2bf(v.y); pb.z = f2bf(v.z); pb.w = f2bf(v.w);
                ((ushort4*)(Ebf + (size_t)n * EMB))[idx] = pb;
                #pragma unroll
                for (int d = 1; d <= BAND; ++d) {
                    float4 u = nb4[d - 1][idx];
                    float dd = v.x * u.x + v.y * u.y + v.z * u.z + v.w * u.w;
                    acc[d] += (d <= dmax) ? dd : 0.f;
                }
            }
        }
        #pragma unroll
        for (int d = 0; d < 12; ++d) acc[d] = wave_sum(acc[d]);
        float dval = 0.f;
        #pragma unroll
        for (int d = 1; d <= BAND; ++d) if (lane == d) dval = acc[d];
        if (lane >= 1 && lane <= BAND) Dots[(size_t)n * 12 + lane] = dval;
        if (lane == 0) invn[n] = 1.0f / sqrtf(acc[0]);
    } else if (b < 1600) {
        const int t = b - 1024;
        const int n0 = (t % 48) * 32;  // over 1536
        const int k0 = (t / 48) * 32;  // over 384
        const int tx = tid & 31, ty = tid >> 5;  // ty 0..7
        #pragma unroll
        for (int q = 0; q < 4; ++q)
            tile[ty + q * 8][tx] = W[(k0 + ty + q * 8) * HE + n0 + tx];
        __syncthreads();
        #pragma unroll
        for (int q = 0; q < 4; ++q)
            Wt[(n0 + ty + q * 8) * EMB + k0 + tx] = f2bf(tile[tx][ty + q * 8]);
    } else {
        const int t = b - 1600;
        ((float4*)attacc)[t * 256 + tid] = make_float4(0.f, 0.f, 0.f, 0.f);
    }
}

// -------------------------------------------- X = E @ W (bf16 MFMA) + fused att dots
// Round-4: latency-hiding restructure of the K-loop (the measured bottleneck class):
//  * 128x64 C-tiles -> 24x32 = 768 blocks = exactly 3 blocks/CU (was 384 = 1.5/CU,
//    half the CUs idle for half the time). LDS 24 KB total (2 buffers).
//  * 2-phase double-buffer (T3 minimum): STAGE(next) issued BEFORE ds_read+MFMA of
//    current buffer; ONE barrier per K-step. The vmcnt(0) drain at the barrier now
//    finds loads that had the whole compute phase in flight.
//  * Staging addressing is round-3's verified pattern: linear LDS dest (gl2lds
//    requirement), 64B-coalesced global segments, source-chunk XOR swizzle
//    (lane&3)^((lane>>3)&3) matched by read-side (quad^((l16>>1)&3)) -> 2-way
//    bank access (free, m136).
__global__ __launch_bounds__(256) void gemm_attn(const unsigned short* __restrict__ Ebf,
                                                 const unsigned short* __restrict__ Wt,
                                                 const float* __restrict__ attS,
                                                 const float* __restrict__ attD,
                                                 unsigned short* __restrict__ Xb,
                                                 float* __restrict__ asrc,
                                                 float* __restrict__ adst) {
    __shared__ unsigned short As[2 * 128 * 32];  // 2 x 8 KB, 128 rows x 32 k each
    __shared__ unsigned short Bs[2 * 64 * 32];   // 2 x 4 KB, 64 rows x 32 k each
    const int tid = threadIdx.x;
    const int lane = tid & 63;
    const int wave = tid >> 6;
    const int m0 = blockIdx.y * 128;
    const int n0 = blockIdx.x * 64;
    const int wrow = (wave >> 1) * 64;   // wave's row offset in C tile (2x2 wave grid)
    const int wcol = (wave & 1) * 32;    // wave's col offset
    const int quad = lane >> 4;
    const int l16 = lane & 15;

    // staging: row = base + lane>>2 (16 rows/issue), source chunk swizzled within
    // the row's 64B segment: (lane&3) ^ s(row), s(row) = (row>>1)&3 = (lane>>3)&3
    const int schunk = (lane & 3) ^ ((lane >> 3) & 3);
    const char* Ab = (const char*)Ebf + (size_t)(m0 + wave * 32 + (lane >> 2)) * 768 + schunk * 16;
    const char* Bb = (const char*)Wt  + (size_t)(n0 + wave * 16 + (lane >> 2)) * 768 + schunk * 16;
    char* AsW = (char*)As + wave * 2048;   // wave's 32-row slice (2 issues of 16 rows)
    char* BsW = (char*)Bs + wave * 1024;   // wave's 16-row slice (1 issue)

    // fragment read byte offset within row: (quad ^ s(row))*16, s(row)=(l16>>1)&3
    const int rchunk = (quad ^ ((l16 >> 1) & 3)) * 16;

    f32x4 acc[4][2];
    #pragma unroll
    for (int i = 0; i < 4; ++i)
        #pragma unroll
        for (int j = 0; j < 2; ++j) acc[i][j] = 0.f;

    // prologue: stage K-step 0 into buffer 0
    gl2lds16(Ab,            AsW);
    gl2lds16(Ab + 16 * 768, AsW + 1024);
    gl2lds16(Bb,            BsW);
    __syncthreads();

    int cur = 0;
    for (int kt = 0; kt < 12; ++kt) {
        // issue next-step staging FIRST: latency hides under this step's compute;
        // the single end-of-step barrier (vmcnt(0)+lgkmcnt(0)) completes it.
        if (kt < 11) {
            const int kb = (kt + 1) * 64;
            const int bufo = (cur ^ 1) * 8192;
            const int bufoB = (cur ^ 1) * 4096;
            gl2lds16(Ab + kb,            AsW + bufo);
            gl2lds16(Ab + kb + 16 * 768, AsW + bufo + 1024);
            gl2lds16(Bb + kb,            BsW + bufoB);
        }

        const char* aBase = (const char*)As + cur * 8192;
        const char* bBase = (const char*)Bs + cur * 4096;
        bf16x8 af[4], bfr[2];
        #pragma unroll
        for (int t = 0; t < 4; ++t)
            af[t] = *(const bf16x8*)(aBase + (wrow + t * 16 + l16) * 64 + rchunk);
        #pragma unroll
        for (int t = 0; t < 2; ++t)
            bfr[t] = *(const bf16x8*)(bBase + (wcol + t * 16 + l16) * 64 + rchunk);
        #pragma unroll
        for (int ti = 0; ti < 4; ++ti)
            #pragma unroll
            for (int tj = 0; tj < 2; ++tj)
                acc[ti][tj] = __builtin_amdgcn_mfma_f32_16x16x32_bf16(
                    af[ti], bfr[tj], acc[ti][tj], 0, 0, 0);

        __syncthreads();   // drains vmcnt (next buffer staged) + all reads of cur done
        cur ^= 1;
    }

    // epilogue 1: att partials (cols n0+wcol..+31 lie within one head; 384 = 12*32)
    const int hblk = (n0 + wcol) / EMB;
    float aS[2], aD[2];
    #pragma unroll
    for (int tj = 0; tj < 2; ++tj) {
        int col = n0 + wcol + tj * 16 + l16;
        aS[tj] = attS[col];
        aD[tj] = attD[col];
    }
    #pragma unroll
    for (int ti = 0; ti < 4; ++ti)
        #pragma unroll
        for (int r = 0; r < 4; ++r) {
            float ps = 0.f, pd = 0.f;
            #pragma unroll
            for (int tj = 0; tj < 2; ++tj) {
                float v = acc[ti][tj][r];
                ps += v * aS[tj];
                pd += v * aD[tj];
            }
            #pragma unroll
            for (int off = 1; off < 16; off <<= 1) {
                ps += __shfl_xor(ps, off, 64);
                pd += __shfl_xor(pd, off, 64);
            }
            if (l16 == 0) {
                int row = m0 + wrow + ti * 16 + quad * 4 + r;
                atomicAdd(&asrc[row * HEADS + hblk], ps);
                atomicAdd(&adst[row * HEADS + hblk], pd);
            }
        }

    // epilogue 2: Xb write (D row = quad*4+reg, col = l16)
    #pragma unroll
    for (int ti = 0; ti < 4; ++ti)
        #pragma unroll
        for (int tj = 0; tj < 2; ++tj) {
            int col = n0 + wcol + tj * 16 + l16;
            #pragma unroll
            for (int r = 0; r < 4; ++r) {
                int row = m0 + wrow + ti * 16 + quad * 4 + r;
                Xb[row * HE + col] = f2bf(acc[ti][tj][r]);
            }
        }
}

// ------------------- wave-per-node: flags from precomputed dots, softmax, aggregate
__global__ __launch_bounds__(256) void band_attn(const float* __restrict__ invn,
                                                 const float* __restrict__ Dots,
                                                 const float* __restrict__ asrc,
                                                 const float* __restrict__ adst,
                                                 const unsigned short* __restrict__ Xb,
                                                 const float* __restrict__ bias,
                                                 float* __restrict__ out) {
    __shared__ float sAl[4][BW][4];   // [wave][jo][h], 16B-aligned rows
    __shared__ int sList[4][24];
    const int tid = threadIdx.x, lane = tid & 63, w = tid >> 6;
    const int i = blockIdx.x * 4 + w;
    const int jo = lane;
    const int j = i - BAND + jo;
    const bool inb = (jo < BW) && (j >= 0) && (j < N_SPANS);
    const int jc = inb ? j : i;

    // fetch precomputed symmetric dot
    float dotv = 0.f;
    if (inb) {
        if (jo < BAND)      dotv = Dots[(size_t)j * 12 + (BAND - jo)];  // dot(j,i)
        else if (jo > BAND) dotv = Dots[(size_t)i * 12 + (jo - BAND)];
    }
    bool flag;
    if (jo == BAND) {
        flag = true;  // diagonal: cos=1 > 0.1 always
    } else {
        int dd = jo < BAND ? BAND - jo : jo - BAND;
        float a = ((dotv * invn[i]) * invn[jc]) * expf(-(float)dd * 0.2f);
        flag = inb && (a > 0.1f);
    }

    unsigned long long mbits = __ballot(flag);
    const int cnt = __popcll(mbits);
    const int rank = __popcll(mbits & ((1ull << jo) - 1ull));
    if (flag) sList[w][rank] = jo;

    // per-head masked softmax across the wave's 23 band lanes
    const float4 ad = ((const float4*)adst)[i];          // wave-uniform
    const float4 as = inb ? ((const float4*)asrc)[jc] : make_float4(0.f, 0.f, 0.f, 0.f);
    float al[4];
    #pragma unroll
    for (int h = 0; h < 4; ++h) {
        float z = (&ad.x)[h] + (&as.x)[h];
        z = (z >= 0.f) ? z : 0.2f * z;                   // leaky_relu 0.2
        float lg = flag ? z : -INFINITY;
        float mx = wave_max(lg);                         // diagonal present -> finite
        float ex = flag ? expf(lg - mx) : 0.f;
        float sm = wave_sum(ex);
        al[h] = ex / sm;
    }
    if (flag) *(float4*)&sAl[w][jo][0] = make_float4(al[0], al[1], al[2], al[3]);
    // same-wave LDS producer/consumer: no barrier needed (compiler inserts lgkmcnt)

    // vectorized gather: ushort4 head-slices (4x fewer loads than scalar)
    #pragma unroll
    for (int mq = 0; mq < 2; ++mq) {
        const int e4 = mq * 64 + lane;   // ushort4/float4 index over 96
        if (e4 < 96) {
            float4 a = make_float4(0.f, 0.f, 0.f, 0.f);
            for (int ii = 0; ii < cnt; ++ii) {
                const int joL = sList[w][ii];
                const int jj = i - BAND + joL;
                const float4 a4 = *(const float4*)&sAl[w][joL][0];
                const ushort4* xr = (const ushort4*)(Xb + (size_t)jj * HE);
                ushort4 h0 = xr[e4], h1 = xr[e4 + 96], h2 = xr[e4 + 192], h3 = xr[e4 + 288];
                a.x += a4.x * bf2f(h0.x) + a4.y * bf2f(h1.x) + a4.z * bf2f(h2.x) + a4.w * bf2f(h3.x);
                a.y += a4.x * bf2f(h0.y) + a4.y * bf2f(h1.y) + a4.z * bf2f(h2.y) + a4.w * bf2f(h3.y);
                a.z += a4.x * bf2f(h0.z) + a4.y * bf2f(h1.z) + a4.z * bf2f(h2.z) + a4.w * bf2f(h3.z);
                a.w += a4.x * bf2f(h0.w) + a4.y * bf2f(h1.w) + a4.z * bf2f(h2.w) + a4.w * bf2f(h3.w);
            }
            const float4 bv = ((const float4*)bias)[e4];
            float4 o;
            o.x = 0.25f * a.x + bv.x;
            o.y = 0.25f * a.y + bv.y;
            o.z = 0.25f * a.z + bv.z;
            o.w = 0.25f * a.w + bv.w;
            ((float4*)(out + (size_t)i * EMB))[e4] = o;
        }
    }
}

extern "C" void kernel_launch(void* const* d_in, const int* in_sizes, int n_in,
                              void* d_out, int out_size, void* d_ws, size_t ws_size,
                              hipStream_t stream) {
    const float* E       = (const float*)d_in[0];
    // d_in[1] span_positions: unused by the reference computation
    const float* W       = (const float*)d_in[2];
    const float* att_src = (const float*)d_in[3];
    const float* att_dst = (const float*)d_in[4];
    const float* bias    = (const float*)d_in[5];
    float* out = (float*)d_out;

    char* ws = (char*)d_ws;
    unsigned short* Xb  = (unsigned short*)ws;                 // 0        .. 12582912
    unsigned short* Ebf = (unsigned short*)(ws + 12582912);    // 3145728
    unsigned short* Wt  = (unsigned short*)(ws + 15728640);    // 1179648
    float* invn         = (float*)(ws + 16908288);             // 16384
    float* asrc         = (float*)(ws + 16924672);             // 65536 (adst contiguous after)
    float* adst         = (float*)(ws + 16990208);             // 65536
    float* Dots         = (float*)(ws + 17055744);             // 4096*12*4 = 196608

    prep<<<1632, 256, 0, stream>>>(E, W, Ebf, Wt, invn, Dots, asrc /* zeroes asrc+adst */);
    gemm_attn<<<dim3(24, 32), 256, 0, stream>>>(Ebf, Wt, att_src, att_dst, Xb, asrc, adst);
    band_attn<<<1024, 256, 0, stream>>>(invn, Dots, asrc, adst, Xb, bias, out);
}

// Round 5
// 99.554 us; speedup vs baseline: 1.1966x; 1.1966x over previous
//
#include <hip/hip_runtime.h>
#include <hip/hip_bf16.h>
#include <math.h>

#define N_SPANS 4096
#define EMB 384
#define HEADS 4
#define HE (HEADS * EMB)   // 1536
#define BAND 11            // exp(-12/5)=0.0907 < 0.1 => |i-j|>=12 never passes threshold
#define BW (2 * BAND + 1)  // 23

typedef short bf16x8 __attribute__((ext_vector_type(8)));
typedef short bf16x4 __attribute__((ext_vector_type(4)));
typedef float f32x4 __attribute__((ext_vector_type(4)));

__device__ __forceinline__ unsigned short f2bf(float f) {
    union { float f; unsigned u; } x; x.f = f;
    unsigned r = x.u + 0x7fffu + ((x.u >> 16) & 1u);  // RNE
    return (unsigned short)(r >> 16);
}
__device__ __forceinline__ float bf2f(unsigned short u) {
    union { unsigned u; float f; } x; x.u = ((unsigned)u) << 16; return x.f;
}

__device__ __forceinline__ float wave_sum(float v) {
    #pragma unroll
    for (int off = 32; off; off >>= 1) v += __shfl_xor(v, off, 64);
    return v;
}
__device__ __forceinline__ float wave_max(float v) {
    #pragma unroll
    for (int off = 32; off; off >>= 1) v = fmaxf(v, __shfl_xor(v, off, 64));
    return v;
}

__device__ __forceinline__ bf16x4 pack4(float a, float b, float c, float d) {
    bf16x4 r;
    r[0] = (short)f2bf(a); r[1] = (short)f2bf(b);
    r[2] = (short)f2bf(c); r[3] = (short)f2bf(d);
    return r;
}

// ================== mega kernel: self-contained GEMM + concurrent band dots =====
// blocks [0,384):   GEMM tile (m0,n0) staged DIRECTLY from E (f32->bf16 cast) and
//                   W (in-register 4x4 transpose) -> no prep dependency, no Ebf/Wt.
//                   Att partials combined in LDS, one deterministic store per
//                   (slice p = nt%3, head h = nt/3) -> no global atomics/zeroing.
// blocks [384,1408): band-dot blocks (invn, Dots) run CONCURRENTLY on other CUs.
__global__ __launch_bounds__(256) void mega(const float* __restrict__ E,
                                            const float* __restrict__ W,
                                            const float* __restrict__ attS,
                                            const float* __restrict__ attD,
                                            unsigned short* __restrict__ Xb,
                                            float* __restrict__ invn,
                                            float* __restrict__ Dots,
                                            float* __restrict__ asrcP,
                                            float* __restrict__ adstP) {
    __shared__ unsigned short As[128 * 32];  // 8 KB, row-major 64B rows, chunk-swizzled
    __shared__ unsigned short Bs[128 * 32];  // 8 KB (cols of W = rows here)
    __shared__ float sAS[128], sAD[128];     // per-row att partials (single head/block)
    const int b = blockIdx.x;
    const int tid = threadIdx.x;
    const int lane = tid & 63, w = tid >> 6;

    if (b < 384) {
        const int nt = b % 12;               // n-tile (col tile)
        const int m0 = (b / 12) * 128;
        const int n0 = nt * 128;
        const int wave = w;
        const int quad = lane >> 4;
        const int l16 = lane & 15;
        const int wr = (wave >> 1) * 64;
        const int wc = (wave & 1) * 64;

        if (tid < 128) { sAS[tid] = 0.f; sAD[tid] = 0.f; }  // done before 1st barrier

        // ---- A staging map (per thread, step-invariant): 4 row-groups --------
        // thread: kAe = (tid&7)*4 k-elems, rA = tid>>3 (+q*32). Global: 128B/row
        // contiguous per 8-lane group -> coalesced. LDS: logical chunk kAe>>3 of
        // row stored at (chunk ^ s(row))*16, s(row)=(row>>1)&3 (q*32 doesn't
        // change s). Matches round-3's verified read swizzle.
        const int kAe = (tid & 7) * 4;
        const int rA = tid >> 3;                       // 0..31
        const int sA = (rA >> 1) & 3;
        const int cA = kAe >> 3;
        const unsigned aByte = rA * 64 + ((cA ^ sA) * 16) + (tid & 1) * 8;
        const float* Ag = E + (size_t)(m0 + rA) * EMB + kAe;

        // ---- B staging map: 4x4 in-register transpose of W -------------------
        // thread: gB = tid&31 (4 cols), kgB = tid>>5 (4 k). Global: 512B/k-row
        // contiguous -> coalesced. Write col c, k-elems kgB*4..+3: logical chunk
        // kgB>>1, half (kgB&1)*8, swizzle s(c)=(c>>1)&3.
        const int gB = tid & 31, kgB = tid >> 5;
        const float* Bg = W + (size_t)(kgB * 4) * HE + n0 + gB * 4;

        const int rchunk = (quad ^ ((l16 >> 1) & 3)) * 16;   // frag read (round-3)

        f32x4 acc[4][4];
        #pragma unroll
        for (int i = 0; i < 4; ++i)
            #pragma unroll
            for (int j = 0; j < 4; ++j) acc[i][j] = 0.f;

        float4 fa[4], fb[4];
        // prologue: load K-step 0 into regs
        #pragma unroll
        for (int q = 0; q < 4; ++q)
            fa[q] = *(const float4*)(Ag + (size_t)q * 32 * EMB);
        #pragma unroll
        for (int i = 0; i < 4; ++i)
            fb[i] = *(const float4*)(Bg + (size_t)i * HE);

        for (int kt = 0; kt < 12; ++kt) {
            // ---- write staged regs to LDS (cast / transpose) ----
            #pragma unroll
            for (int q = 0; q < 4; ++q)
                *(bf16x4*)((char*)As + q * 2048 + aByte) =
                    pack4(fa[q].x, fa[q].y, fa[q].z, fa[q].w);
            #pragma unroll
            for (int j = 0; j < 4; ++j) {
                const int c = gB * 4 + j;
                const int sB = (c >> 1) & 3;
                *(bf16x4*)((char*)Bs + c * 64 + (((kgB >> 1) ^ sB) * 16) + (kgB & 1) * 8) =
                    pack4((&fb[0].x)[j], (&fb[1].x)[j], (&fb[2].x)[j], (&fb[3].x)[j]);
            }
            __syncthreads();

            // ---- issue next step's global loads (hide under MFMA, T14) ----
            if (kt < 11) {
                const int ko = (kt + 1) * 32;
                #pragma unroll
                for (int q = 0; q < 4; ++q)
                    fa[q] = *(const float4*)(Ag + (size_t)q * 32 * EMB + ko);
                #pragma unroll
                for (int i = 0; i < 4; ++i)
                    fb[i] = *(const float4*)(Bg + (size_t)(ko + i) * HE);
            }

            // ---- fragments + MFMA (identical to round-3) ----
            bf16x8 af[4], bfr[4];
            #pragma unroll
            for (int t = 0; t < 4; ++t) {
                af[t]  = *(const bf16x8*)((const char*)As + (wr + t * 16 + l16) * 64 + rchunk);
                bfr[t] = *(const bf16x8*)((const char*)Bs + (wc + t * 16 + l16) * 64 + rchunk);
            }
            #pragma unroll
            for (int ti = 0; ti < 4; ++ti)
                #pragma unroll
                for (int tj = 0; tj < 4; ++tj)
                    acc[ti][tj] = __builtin_amdgcn_mfma_f32_16x16x32_bf16(
                        af[ti], bfr[tj], acc[ti][tj], 0, 0, 0);

            __syncthreads();   // all frag reads done before next ds_write
        }

        // ---- epilogue 1: att partials -> LDS combine -> deterministic store ----
        float aS[4], aD[4];
        #pragma unroll
        for (int tj = 0; tj < 4; ++tj) {
            int col = n0 + wc + tj * 16 + l16;
            aS[tj] = attS[col];
            aD[tj] = attD[col];
        }
        #pragma unroll
        for (int ti = 0; ti < 4; ++ti)
            #pragma unroll
            for (int r = 0; r < 4; ++r) {
                float ps = 0.f, pd = 0.f;
                #pragma unroll
                for (int tj = 0; tj < 4; ++tj) {
                    float v = acc[ti][tj][r];
                    ps += v * aS[tj];
                    pd += v * aD[tj];
                }
                #pragma unroll
                for (int off = 1; off < 16; off <<= 1) {
                    ps += __shfl_xor(ps, off, 64);
                    pd += __shfl_xor(pd, off, 64);
                }
                if (l16 == 0) {
                    int lrow = wr + ti * 16 + quad * 4 + r;   // 2 waves/lrow (wc halves)
                    atomicAdd(&sAS[lrow], ps);
                    atomicAdd(&sAD[lrow], pd);
                }
            }
        __syncthreads();
        {
            const int p = nt % 3, h = nt / 3;   // slice, head (128-col tile in 1 head)
            if (tid < 128)
                asrcP[((size_t)p * N_SPANS + m0 + tid) * HEADS + h] = sAS[tid];
            else
                adstP[((size_t)p * N_SPANS + m0 + tid - 128) * HEADS + h] = sAD[tid - 128];
        }

        // ---- epilogue 2: Xb write (D row = quad*4+reg, col = l16) ----
        #pragma unroll
        for (int ti = 0; ti < 4; ++ti)
            #pragma unroll
            for (int tj = 0; tj < 4; ++tj) {
                int col = n0 + wc + tj * 16 + l16;
                #pragma unroll
                for (int r = 0; r < 4; ++r) {
                    int row = m0 + wr + ti * 16 + quad * 4 + r;
                    Xb[row * HE + col] = f2bf(acc[ti][tj][r]);
                }
            }
    } else {
        // ---------------- band-dot blocks: invn + forward dots d=1..11 ---------
        const int n = (b - 384) * 4 + w;
        const float4* er4 = (const float4*)(E + (size_t)n * EMB);
        const int dmax = (n >= N_SPANS - BAND) ? (N_SPANS - 1 - n) : BAND;  // wave-uniform
        const float4* nb4[BAND];
        #pragma unroll
        for (int d = 1; d <= BAND; ++d) {
            int j = n + d; if (j > N_SPANS - 1) j = N_SPANS - 1;  // clamped, in-bounds
            nb4[d - 1] = (const float4*)(E + (size_t)j * EMB);
        }
        float acc[12];
        #pragma unroll
        for (int d = 0; d < 12; ++d) acc[d] = 0.f;
        #pragma unroll
        for (int mq = 0; mq < 2; ++mq) {
            const int idx = mq * 64 + lane;   // float4 index over 96
            if (idx < 96) {
                float4 v = er4[idx];
                acc[0] += v.x * v.x + v.y * v.y + v.z * v.z + v.w * v.w;
                #pragma unroll
                for (int d = 1; d <= BAND; ++d) {
                    float4 u = nb4[d - 1][idx];
                    float dd = v.x * u.x + v.y * u.y + v.z * u.z + v.w * u.w;
                    acc[d] += (d <= dmax) ? dd : 0.f;
                }
            }
        }
        #pragma unroll
        for (int d = 0; d < 12; ++d) acc[d] = wave_sum(acc[d]);
        float dval = 0.f;
        #pragma unroll
        for (int d = 1; d <= BAND; ++d) if (lane == d) dval = acc[d];
        if (lane >= 1 && lane <= BAND) Dots[(size_t)n * 12 + lane] = dval;
        if (lane == 0) invn[n] = 1.0f / sqrtf(acc[0]);
    }
}

// ------------------- wave-per-node: flags from precomputed dots, softmax, aggregate
__global__ __launch_bounds__(256) void band_attn(const float* __restrict__ invn,
                                                 const float* __restrict__ Dots,
                                                 const float* __restrict__ asrcP,
                                                 const float* __restrict__ adstP,
                                                 const unsigned short* __restrict__ Xb,
                                                 const float* __restrict__ bias,
                                                 float* __restrict__ out) {
    __shared__ float sAl[4][BW][4];   // [wave][jo][h], 16B-aligned rows
    __shared__ int sList[4][24];
    const int tid = threadIdx.x, lane = tid & 63, w = tid >> 6;
    const int i = blockIdx.x * 4 + w;
    const int jo = lane;
    const int j = i - BAND + jo;
    const bool inb = (jo < BW) && (j >= 0) && (j < N_SPANS);
    const int jc = inb ? j : i;

    // fetch precomputed symmetric dot
    float dotv = 0.f;
    if (inb) {
        if (jo < BAND)      dotv = Dots[(size_t)j * 12 + (BAND - jo)];  // dot(j,i)
        else if (jo > BAND) dotv = Dots[(size_t)i * 12 + (jo - BAND)];
    }
    bool flag;
    if (jo == BAND) {
        flag = true;  // diagonal: cos=1 > 0.1 always
    } else {
        int dd = jo < BAND ? BAND - jo : jo - BAND;
        float a = ((dotv * invn[i]) * invn[jc]) * expf(-(float)dd * 0.2f);
        flag = inb && (a > 0.1f);
    }

    unsigned long long mbits = __ballot(flag);
    const int cnt = __popcll(mbits);
    const int rank = __popcll(mbits & ((1ull << jo) - 1ull));
    if (flag) sList[w][rank] = jo;

    // att sums: 3 deterministic slices (replaces atomics+zeroing)
    const float4* S4 = (const float4*)asrcP;   // [3][N] float4 (4 heads)
    const float4* D4 = (const float4*)adstP;
    float4 ad, as;
    {
        float4 a0 = D4[i], a1 = D4[N_SPANS + i], a2 = D4[2 * N_SPANS + i];  // wave-uniform
        ad = make_float4(a0.x + a1.x + a2.x, a0.y + a1.y + a2.y,
                         a0.z + a1.z + a2.z, a0.w + a1.w + a2.w);
        if (inb) {
            float4 s0 = S4[jc], s1 = S4[N_SPANS + jc], s2 = S4[2 * N_SPANS + jc];
            as = make_float4(s0.x + s1.x + s2.x, s0.y + s1.y + s2.y,
                             s0.z + s1.z + s2.z, s0.w + s1.w + s2.w);
        } else {
            as = make_float4(0.f, 0.f, 0.f, 0.f);
        }
    }
    float al[4];
    #pragma unroll
    for (int h = 0; h < 4; ++h) {
        float z = (&ad.x)[h] + (&as.x)[h];
        z = (z >= 0.f) ? z : 0.2f * z;                   // leaky_relu 0.2
        float lg = flag ? z : -INFINITY;
        float mx = wave_max(lg);                         // diagonal present -> finite
        float ex = flag ? expf(lg - mx) : 0.f;
        float sm = wave_sum(ex);
        al[h] = ex / sm;
    }
    if (flag) *(float4*)&sAl[w][jo][0] = make_float4(al[0], al[1], al[2], al[3]);
    // same-wave LDS producer/consumer: no barrier needed (compiler inserts lgkmcnt)

    // vectorized gather: ushort4 head-slices (4x fewer loads than scalar)
    #pragma unroll
    for (int mq = 0; mq < 2; ++mq) {
        const int e4 = mq * 64 + lane;   // ushort4/float4 index over 96
        if (e4 < 96) {
            float4 a = make_float4(0.f, 0.f, 0.f, 0.f);
            for (int ii = 0; ii < cnt; ++ii) {
                const int joL = sList[w][ii];
                const int jj = i - BAND + joL;
                const float4 a4 = *(const float4*)&sAl[w][joL][0];
                const ushort4* xr = (const ushort4*)(Xb + (size_t)jj * HE);
                ushort4 h0 = xr[e4], h1 = xr[e4 + 96], h2 = xr[e4 + 192], h3 = xr[e4 + 288];
                a.x += a4.x * bf2f(h0.x) + a4.y * bf2f(h1.x) + a4.z * bf2f(h2.x) + a4.w * bf2f(h3.x);
                a.y += a4.x * bf2f(h0.y) + a4.y * bf2f(h1.y) + a4.z * bf2f(h2.y) + a4.w * bf2f(h3.y);
                a.z += a4.x * bf2f(h0.z) + a4.y * bf2f(h1.z) + a4.z * bf2f(h2.z) + a4.w * bf2f(h3.z);
                a.w += a4.x * bf2f(h0.w) + a4.y * bf2f(h1.w) + a4.z * bf2f(h2.w) + a4.w * bf2f(h3.w);
            }
            const float4 bv = ((const float4*)bias)[e4];
            float4 o;
            o.x = 0.25f * a.x + bv.x;
            o.y = 0.25f * a.y + bv.y;
            o.z = 0.25f * a.z + bv.z;
            o.w = 0.25f * a.w + bv.w;
            ((float4*)(out + (size_t)i * EMB))[e4] = o;
        }
    }
}

extern "C" void kernel_launch(void* const* d_in, const int* in_sizes, int n_in,
                              void* d_out, int out_size, void* d_ws, size_t ws_size,
                              hipStream_t stream) {
    const float* E       = (const float*)d_in[0];
    // d_in[1] span_positions: unused by the reference computation
    const float* W       = (const float*)d_in[2];
    const float* att_src = (const float*)d_in[3];
    const float* att_dst = (const float*)d_in[4];
    const float* bias    = (const float*)d_in[5];
    float* out = (float*)d_out;

    char* ws = (char*)d_ws;
    unsigned short* Xb = (unsigned short*)ws;              // 0        .. 12582912
    float* invn        = (float*)(ws + 12582912);          // 16384
    float* Dots        = (float*)(ws + 12599296);          // 196608
    float* asrcP       = (float*)(ws + 12795904);          // 3*4096*4*4 = 196608
    float* adstP       = (float*)(ws + 12992512);          // 196608

    mega<<<1408, 256, 0, stream>>>(E, W, att_src, att_dst, Xb, invn, Dots, asrcP, adstP);
    band_attn<<<1024, 256, 0, stream>>>(invn, Dots, asrcP, adstP, Xb, bias, out);
}